// Round 3
// baseline (1392.138 us; speedup 1.0000x reference)
//
#include <hip/hip_runtime.h>
#include <cstdint>

#define TT 1024
#define BB 512
#define KK 128

typedef __attribute__((ext_vector_type(8))) short short8;
typedef __attribute__((ext_vector_type(4))) float f4;

// float -> bf16 round-to-nearest-even (values are positive, finite)
__device__ __forceinline__ unsigned short f2bf(float x) {
  unsigned u = __float_as_uint(x);
  u += 0x7FFF + ((u >> 16) & 1);
  return (unsigned short)(u >> 16);
}

// Workgroup barrier that waits ONLY on LDS ops (lgkmcnt(0)); leaves global
// loads (vmcnt) in flight across the barrier so the emission prefetch for
// step t+1 is not drained every step (__syncthreads would s_waitcnt vmcnt(0)).
__device__ __forceinline__ void lgkm_barrier() {
  __atomic_signal_fence(__ATOMIC_SEQ_CST);
  __builtin_amdgcn_s_waitcnt(0xC07F);  // vmcnt=63(no wait), expcnt=7, lgkmcnt=0
  __builtin_amdgcn_s_barrier();
  __atomic_signal_fence(__ATOMIC_SEQ_CST);
}

// ---------------------------------------------------------------------------
// MFMA forward algorithm. grid = 32 blocks x 256 threads; block owns 16 batch
// rows. Per step: S[16,128] = P[16,128] x E[128,128] via mfma_f32_16x16x32_bf16
// (E = exp(trans) static in B-frags; wave w owns cols [32w,32w+32) = 2 N-tiles).
//
// Numerics (bounded-state scheme, one barrier/step):
//   state rel (C-layout), invariant rel in [~-7, ~+11]:
//     p(t-1) = exp(rel(t-1))            (no normalizer needed - rel bounded)
//     s_j    = sum_i p_i E_ij           (MFMA, fp32 accum)
//     rel(t) = mask ? log s_j + em_j - M_t : rel(t-1)
//     base  += mask ? M_t : 0
//   where M_t = exact row-max of rel(t-1), computed pre-barrier (4-round
//   quad shuffle-max -> mxs), combined POST-barrier (off the exp path).
//   Since log s in [M_t-0.11, M_t+4.97], rel(t) in [em-0.11, em+4.97]: bounded.
// P-tile transpose through LDS: stride 136 bf16 (16B-aligned rows, even bank
// spread for ds_read_b128 A-frags). Double-buffered Pt/mxs => single barrier.
// ---------------------------------------------------------------------------
__global__ __launch_bounds__(256, 1) void crf_forward(
    const float* __restrict__ em, const float* __restrict__ mask,
    const float* __restrict__ start_t, const float* __restrict__ trans,
    const float* __restrict__ end_t, float* __restrict__ logz)
{
  const int tid  = threadIdx.x;
  const int w    = __builtin_amdgcn_readfirstlane(tid >> 6);  // wave 0..3
  const int lane = tid & 63;
  const int q    = lane >> 4;   // quad 0..3
  const int lo   = lane & 15;
  const int b0   = blockIdx.x * 16;

  __shared__ __align__(16) unsigned short Pt[2][16 * 136];
  __shared__ __align__(16) float mxs[2][16][4];
  __shared__ __align__(16) float psm[16][4];
  __shared__ float bs[16];

  const int n0      = w * 32 + lo;            // col for nt=0; +16 for nt=1
  const int laneoff = q * 4 * KK + n0;        // + reg*KK (+16 for nt=1)

  // ---- issue prologue global loads early (overlap with E-frag build) ----
  const float* em0p = em + (size_t)b0 * KK;
  const float* em1p = em + ((size_t)BB + b0) * KK;
  float e0v[4][2], emc[4][2], mkc[4];
#pragma unroll
  for (int r = 0; r < 4; ++r) {
    e0v[r][0] = em0p[laneoff + r * KK];
    e0v[r][1] = em0p[laneoff + r * KK + 16];
    emc[r][0] = em1p[laneoff + r * KK];
    emc[r][1] = em1p[laneoff + r * KK + 16];
    mkc[r]    = mask[BB + b0 + 4 * q + r];
  }
  const float st0 = start_t[n0], st1 = start_t[n0 + 16];

  // ---- E fragments (B-operand layout: n = lane&15 within tile, k = 32kt+8q+j)
  short8 Bf[2][4];
#pragma unroll
  for (int nt = 0; nt < 2; ++nt)
#pragma unroll
    for (int kt = 0; kt < 4; ++kt) {
      short8 v;
#pragma unroll
      for (int j = 0; j < 8; ++j) {
        const int k = kt * 32 + q * 8 + j;
        v[j] = (short)f2bf(__expf(trans[(size_t)k * KK + n0 + nt * 16]));
      }
      Bf[nt][kt] = v;
    }

  // ---- initial state: rel(0) = start + em(0)  (C-layout: row 4q+reg, col n)
  float rel[4][2], base[4];
#pragma unroll
  for (int r = 0; r < 4; ++r) {
    rel[r][0] = st0 + e0v[r][0];
    rel[r][1] = st1 + e0v[r][1];
    base[r]   = 0.f;
  }

  // ---- prologue write phase (buf 0): p = exp(rel0), quad-max -> mxs
#pragma unroll
  for (int r = 0; r < 4; ++r) {
    const int m = 4 * q + r;
    Pt[0][m * 136 + n0]      = f2bf(__expf(rel[r][0]));
    Pt[0][m * 136 + n0 + 16] = f2bf(__expf(rel[r][1]));
  }
  {
    float vm[4];
#pragma unroll
    for (int r = 0; r < 4; ++r) vm[r] = fmaxf(rel[r][0], rel[r][1]);
#pragma unroll
    for (int off = 1; off < 16; off <<= 1)
#pragma unroll
      for (int r = 0; r < 4; ++r) vm[r] = fmaxf(vm[r], __shfl_xor(vm[r], off));
    if (lo == 0)
#pragma unroll
      for (int r = 0; r < 4; ++r) mxs[0][4 * q + r][w] = vm[r];
  }
  lgkm_barrier();

  // ---- prologue read phase: A-frags + M
  short8 Af[4];
  float  Mr[4];
#pragma unroll
  for (int kt = 0; kt < 4; ++kt)
    Af[kt] = *(const short8*)&Pt[0][lo * 136 + kt * 32 + q * 8];
#pragma unroll
  for (int r = 0; r < 4; ++r) {
    const f4 mv = *(const f4*)&mxs[0][4 * q + r][0];
    Mr[r] = fmaxf(fmaxf(mv[0], mv[1]), fmaxf(mv[2], mv[3]));
  }

  float emn[4][2], mkn[4];
  for (int t = 1; t < TT; ++t) {
    const int buf = t & 1;

    // prefetch em/mask for t+1 (stays in flight across the lgkm barrier)
    if (t < TT - 1) {
      const float* emt = em + ((size_t)(t + 1) * BB + b0) * KK;
#pragma unroll
      for (int r = 0; r < 4; ++r) {
        emn[r][0] = emt[laneoff + r * KK];
        emn[r][1] = emt[laneoff + r * KK + 16];
        mkn[r]    = mask[(t + 1) * BB + b0 + 4 * q + r];
      }
    }

    // MFMA: s for this wave's 32 cols (2 N-tiles), K-loop of 4
    f4 a0 = {0.f, 0.f, 0.f, 0.f}, a1 = {0.f, 0.f, 0.f, 0.f};
#pragma unroll
    for (int kt = 0; kt < 4; ++kt) {
      a0 = __builtin_amdgcn_mfma_f32_16x16x32_bf16(Af[kt], Bf[0][kt], a0, 0, 0, 0);
      a1 = __builtin_amdgcn_mfma_f32_16x16x32_bf16(Af[kt], Bf[1][kt], a1, 0, 0, 0);
    }

    // epilogue: rel(t) = mask ? log s + em - M : rel(t-1); base += mask ? M : 0
#pragma unroll
    for (int r = 0; r < 4; ++r) {
      const bool upd = (mkc[r] != 0.f);
      const float l0 = __logf(a0[r]) + emc[r][0] - Mr[r];
      const float l1 = __logf(a1[r]) + emc[r][1] - Mr[r];
      rel[r][0] = upd ? l0 : rel[r][0];
      rel[r][1] = upd ? l1 : rel[r][1];
      base[r]  += upd ? Mr[r] : 0.f;
    }

    // write phase: p = exp(rel) -> Pt[buf]; quad-max(rel) -> mxs[buf]
#pragma unroll
    for (int r = 0; r < 4; ++r) {
      const int m = 4 * q + r;
      Pt[buf][m * 136 + n0]      = f2bf(__expf(rel[r][0]));
      Pt[buf][m * 136 + n0 + 16] = f2bf(__expf(rel[r][1]));
    }
    {
      float vm[4];
#pragma unroll
      for (int r = 0; r < 4; ++r) vm[r] = fmaxf(rel[r][0], rel[r][1]);
#pragma unroll
      for (int off = 1; off < 16; off <<= 1)
#pragma unroll
        for (int r = 0; r < 4; ++r) vm[r] = fmaxf(vm[r], __shfl_xor(vm[r], off));
      if (lo == 0)
#pragma unroll
        for (int r = 0; r < 4; ++r) mxs[buf][4 * q + r][w] = vm[r];
    }

    lgkm_barrier();

    // read phase: next A-frags + fresh M (max of rel(t))
#pragma unroll
    for (int kt = 0; kt < 4; ++kt)
      Af[kt] = *(const short8*)&Pt[buf][lo * 136 + kt * 32 + q * 8];
#pragma unroll
    for (int r = 0; r < 4; ++r) {
      const f4 mv = *(const f4*)&mxs[buf][4 * q + r][0];
      Mr[r] = fmaxf(fmaxf(mv[0], mv[1]), fmaxf(mv[2], mv[3]));
    }

    // rotate prefetch
#pragma unroll
    for (int r = 0; r < 4; ++r) {
      emc[r][0] = emn[r][0];
      emc[r][1] = emn[r][1];
      mkc[r]    = mkn[r];
    }
  }

  // ---- finale: logZ = base + M + log sum_j exp(rel_j + end_j - M)
  {
    const float e0 = end_t[n0], e1 = end_t[n0 + 16];
    float ps[4];
#pragma unroll
    for (int r = 0; r < 4; ++r)
      ps[r] = __expf(rel[r][0] + e0 - Mr[r]) + __expf(rel[r][1] + e1 - Mr[r]);
#pragma unroll
    for (int off = 1; off < 16; off <<= 1)
#pragma unroll
      for (int r = 0; r < 4; ++r) ps[r] += __shfl_xor(ps[r], off);
    if (lo == 0)
#pragma unroll
      for (int r = 0; r < 4; ++r) {
        psm[4 * q + r][w] = ps[r];
        if (w == 0) bs[4 * q + r] = base[r] + Mr[r];
      }
    __syncthreads();
    if (tid < 16) {
      const f4 pv = *(const f4*)&psm[tid][0];
      logz[b0 + tid] = bs[tid] + __logf(pv[0] + pv[1] + pv[2] + pv[3]);
    }
  }
}

// ---------------------------------------------------------------------------
// Gold-path score. grid = B blocks x 256 threads (threads strided over t).
// ---------------------------------------------------------------------------
__global__ __launch_bounds__(256) void crf_path(
    const float* __restrict__ em, const int* __restrict__ tags,
    const float* __restrict__ mask, const float* __restrict__ start_t,
    const float* __restrict__ trans, const float* __restrict__ end_t,
    float* __restrict__ path_out)
{
  const int b = blockIdx.x;
  const int tid = threadIdx.x;
  float acc = 0.f, msum = 0.f;
  for (int t = tid; t < TT; t += 256) {
    const int   tg = tags[t * BB + b];
    const float mk = mask[t * BB + b];
    msum += mk;
    acc = fmaf(em[((size_t)t * BB + b) * KK + tg], mk, acc);
    if (t >= 1) {
      const int tgp = tags[(t - 1) * BB + b];
      acc = fmaf(trans[tgp * KK + tg], mk, acc);
    }
  }
  __shared__ float red_a[4], red_m[4];
#pragma unroll
  for (int off = 32; off; off >>= 1) {
    acc  += __shfl_xor(acc, off);
    msum += __shfl_xor(msum, off);
  }
  if ((tid & 63) == 0) { red_a[tid >> 6] = acc; red_m[tid >> 6] = msum; }
  __syncthreads();
  if (tid == 0) {
    float a  = (red_a[0] + red_a[1]) + (red_a[2] + red_a[3]);
    float ms = (red_m[0] + red_m[1]) + (red_m[2] + red_m[3]);
    const int last = (int)(ms + 0.5f) - 1;
    a += start_t[tags[b]] + end_t[tags[(size_t)last * BB + b]];
    path_out[b] = a;
  }
}

// ---------------------------------------------------------------------------
// Final reduction: out = sum_b (path_b - logz_b). 1 block x 512 threads.
// ---------------------------------------------------------------------------
__global__ __launch_bounds__(512) void crf_final(
    const float* __restrict__ path, const float* __restrict__ logz,
    float* __restrict__ out)
{
  const int tid = threadIdx.x;
  float v = path[tid] - logz[tid];
  __shared__ float red[8];
#pragma unroll
  for (int off = 32; off; off >>= 1) v += __shfl_xor(v, off);
  if ((tid & 63) == 0) red[tid >> 6] = v;
  __syncthreads();
  if (tid == 0) {
    float s = 0.f;
#pragma unroll
    for (int i = 0; i < 8; ++i) s += red[i];
    out[0] = s;
  }
}

extern "C" void kernel_launch(void* const* d_in, const int* in_sizes, int n_in,
                              void* d_out, int out_size, void* d_ws, size_t ws_size,
                              hipStream_t stream) {
  (void)in_sizes; (void)n_in; (void)out_size; (void)ws_size;
  const float* em    = (const float*)d_in[0];
  const int*   tags  = (const int*)  d_in[1];
  const float* mask  = (const float*)d_in[2];
  const float* st    = (const float*)d_in[3];
  const float* trans = (const float*)d_in[4];
  const float* et    = (const float*)d_in[5];
  float* out = (float*)d_out;

  float* ws_path = (float*)d_ws;        // [B]
  float* ws_logz = ws_path + BB;        // [B]

  crf_path   <<<BB, 256, 0, stream>>>(em, tags, mask, st, trans, et, ws_path);
  crf_forward<<<32, 256, 0, stream>>>(em, mask, st, trans, et, ws_logz);
  crf_final  <<<1, 512, 0, stream>>>(ws_path, ws_logz, out);
}

// Round 4
// 1114.020 us; speedup vs baseline: 1.2497x; 1.2497x over previous
//
#include <hip/hip_runtime.h>
#include <cstdint>

#define TT 1024
#define BB 512
#define KK 128
#define ST 136   // LDS row stride in bf16 elems (272 B = 17*16 -> rows stay 16B-aligned)

typedef __attribute__((ext_vector_type(8))) short short8;
typedef __attribute__((ext_vector_type(4))) float f4;

__device__ __forceinline__ unsigned short f2bf_rtne(float x) {
  unsigned u = __float_as_uint(x);
  u += 0x7FFF + ((u >> 16) & 1);
  return (unsigned short)(u >> 16);
}

// pack trunc-bf16(l) into low16, trunc-bf16(h) into high16 — one v_perm_b32
__device__ __forceinline__ unsigned pack_trunc(float l, float h) {
  return __builtin_amdgcn_perm(__float_as_uint(h), __float_as_uint(l), 0x07060302u);
}

// barrier waiting only on LDS (lgkmcnt=0); global prefetch stays in flight
__device__ __forceinline__ void lgkm_barrier() {
  __atomic_signal_fence(__ATOMIC_SEQ_CST);
  __builtin_amdgcn_s_waitcnt(0xC07F);  // vmcnt=63, expcnt=7, lgkmcnt=0
  __builtin_amdgcn_s_barrier();
  __atomic_signal_fence(__ATOMIC_SEQ_CST);
}

// ---------------------------------------------------------------------------
// Linear-space MFMA forward. grid = 32 blocks x 256 threads; block = 16 batch
// rows. Orientation: S^T[128 cols, 16 rows] = E^T x P^T so the MFMA C-layout
// keeps batch row on lane (n = lane&15) — B-frag for the NEXT step needs no
// cross-row move, only a col-regroup through LDS (row-contiguous b64 writes,
// b128 reads).
//   recurrence:  P(t) = (P(t-1) E) . X_t,  X_t = exp(em_t)   [no log/exp in
//   the dependency chain: X built off-chain from 2-deep prefetch]
//   renorm: every 4 steps measure row max (quad shuffles + LDS, piggybacks on
//   the step barrier), apply power-of-2 scale next step; base += k*ln2.
//   masked steps: select old fp32 state per row (exact carry).
// Wave w owns state cols [32w,32w+32) = m-tiles {2w,2w+1}; E-frags static.
// ---------------------------------------------------------------------------
__global__ __launch_bounds__(256, 1) void crf_forward(
    const float* __restrict__ em, const float* __restrict__ mask,
    const float* __restrict__ start_t, const float* __restrict__ trans,
    const float* __restrict__ end_t, float* __restrict__ logz)
{
  const int tid  = threadIdx.x;
  const int w    = __builtin_amdgcn_readfirstlane(tid >> 6);  // wave 0..3
  const int lane = tid & 63;
  const int q    = lane >> 4;    // quad 0..3
  const int lo   = lane & 15;    // batch row within block / col within tile
  const int b0   = blockIdx.x * 16;

  __shared__ __align__(16) unsigned short Pt[2][16 * ST];
  __shared__ __align__(16) float mxs[16][4];
  __shared__ __align__(16) float psm[16][4];

  // this lane's state-col bases: c(mti,r) = 32w + 16*mti + 4q + r
  const int cb0 = 32 * w + 4 * q;
  const int cb1 = cb0 + 16;

  const size_t TS = (size_t)BB * KK;
  const float* emrow = em + (size_t)(b0 + lo) * KK;

  // ---- E fragments (A-operand = E^T): lane holds E[32kt+8q+j][16(2w+mti)+lo]
  short8 Af[2][4];
#pragma unroll
  for (int mti = 0; mti < 2; ++mti) {
    const int col = 16 * (2 * w + mti) + lo;
#pragma unroll
    for (int kt = 0; kt < 4; ++kt) {
      short8 v;
#pragma unroll
      for (int j = 0; j < 8; ++j) {
        const int k = 32 * kt + 8 * q + j;
        v[j] = (short)f2bf_rtne(__expf(trans[(size_t)k * KK + col]));
      }
      Af[mti][kt] = v;
    }
  }

  // ---- initial state P(0) = exp(start + em(0))
  f4 S0, S1;
  float base = 0.f;
  {
    const f4 e0a = *(const f4*)(emrow + cb0);
    const f4 e0b = *(const f4*)(emrow + cb1);
    const f4 st0 = *(const f4*)(start_t + cb0);
    const f4 st1 = *(const f4*)(start_t + cb1);
#pragma unroll
    for (int i = 0; i < 4; ++i) {
      S0[i] = __expf(st0[i] + e0a[i]);
      S1[i] = __expf(st1[i] + e0b[i]);
    }
    *(uint2*)&Pt[0][lo * ST + cb0] =
        make_uint2(pack_trunc(S0[0], S0[1]), pack_trunc(S0[2], S0[3]));
    *(uint2*)&Pt[0][lo * ST + cb1] =
        make_uint2(pack_trunc(S1[0], S1[1]), pack_trunc(S1[2], S1[3]));
  }

  // ---- 2-deep emission/mask prefetch
  f4 eaC = *(const f4*)(emrow + 1 * TS + cb0);
  f4 ebC = *(const f4*)(emrow + 1 * TS + cb1);
  f4 eaN = *(const f4*)(emrow + 2 * TS + cb0);
  f4 ebN = *(const f4*)(emrow + 2 * TS + cb1);
  float mkC = mask[1 * BB + b0 + lo];
  float mkN = mask[2 * BB + b0 + lo];

  for (int t = 1; t < TT; ++t) {
    const int pb = (t & 1) ^ 1;   // buffer holding P(t-1)

    lgkm_barrier();

    // pending renorm (measured at t-1 ≡ 0 mod 4) — off the exp path
    float ps = 1.0f, kln2 = 0.f;
    const bool scale_step = ((t & 3) == 1) && (t > 1);
    if (scale_step) {
      const f4 mv4 = *(const f4*)&mxs[lo][0];
      const float mv = fmaxf(fmaxf(mv4[0], mv4[1]), fmaxf(mv4[2], mv4[3]));
      const int k = (int)(__float_as_uint(mv) >> 23) - 127;
      ps = __uint_as_float((unsigned)(127 - k) << 23);
      kln2 = (float)k * 0.6931471805599453f;
    }

    // B-frags of P(t-1): row lo, cols 32kt+8q..+7 (16B aligned)
    short8 Bf[4];
#pragma unroll
    for (int kt = 0; kt < 4; ++kt)
      Bf[kt] = *(const short8*)&Pt[pb][lo * ST + 32 * kt + 8 * q];

    // prefetch em/mask for t+2 (stays in flight across the lgkm barrier)
    const int tp = (t + 2 < TT) ? (t + 2) : (TT - 1);
    const f4 eaL = *(const f4*)(emrow + (size_t)tp * TS + cb0);
    const f4 ebL = *(const f4*)(emrow + (size_t)tp * TS + cb1);
    const float mkL = mask[tp * BB + b0 + lo];

    // X(t) = exp(em(t)) (* pending scale) — off the MFMA/LDS chain
    f4 X0, X1;
#pragma unroll
    for (int i = 0; i < 4; ++i) { X0[i] = __expf(eaC[i]); X1[i] = __expf(ebC[i]); }
    if (scale_step) { X0 *= ps; X1 *= ps; }

    // S^T tile: acc = E^T * P^T for own 32 cols
    f4 a0 = {0.f, 0.f, 0.f, 0.f}, a1 = {0.f, 0.f, 0.f, 0.f};
#pragma unroll
    for (int kt = 0; kt < 4; ++kt) {
      a0 = __builtin_amdgcn_mfma_f32_16x16x32_bf16(Af[0][kt], Bf[kt], a0, 0, 0, 0);
      a1 = __builtin_amdgcn_mfma_f32_16x16x32_bf16(Af[1][kt], Bf[kt], a1, 0, 0, 0);
    }

    // new state (masked rows carry old fp32 state exactly)
    const bool upd = (mkC != 0.f);
#pragma unroll
    for (int i = 0; i < 4; ++i) {
      const float n0 = a0[i] * X0[i];
      const float n1 = a1[i] * X1[i];
      S0[i] = upd ? n0 : S0[i];
      S1[i] = upd ? n1 : S1[i];
    }
    if (scale_step && upd) base += kln2;

    // pack (1 v_perm per pair, trunc-to-bf16) and stage for next step
    *(uint2*)&Pt[t & 1][lo * ST + cb0] =
        make_uint2(pack_trunc(S0[0], S0[1]), pack_trunc(S0[2], S0[3]));
    *(uint2*)&Pt[t & 1][lo * ST + cb1] =
        make_uint2(pack_trunc(S1[0], S1[1]), pack_trunc(S1[2], S1[3]));

    // renorm measurement every 4 steps (wave-local cols; cross-wave via mxs)
    if ((t & 3) == 0) {
      float mv = fmaxf(fmaxf(fmaxf(S0[0], S0[1]), fmaxf(S0[2], S0[3])),
                       fmaxf(fmaxf(S1[0], S1[1]), fmaxf(S1[2], S1[3])));
      mv = fmaxf(mv, __shfl_xor(mv, 16));
      mv = fmaxf(mv, __shfl_xor(mv, 32));
      if (q == 0) mxs[lo][w] = mv;
    }

    // rotate prefetch
    eaC = eaN; ebC = ebN; eaN = eaL; ebN = ebL;
    mkC = mkN; mkN = mkL;
  }

  // ---- finale: logZ[row] = base + log( sum_j P_j * exp(end_j) )
  {
    const f4 ed0 = *(const f4*)(end_t + cb0);
    const f4 ed1 = *(const f4*)(end_t + cb1);
    float s = 0.f;
#pragma unroll
    for (int i = 0; i < 4; ++i)
      s += S0[i] * __expf(ed0[i]) + S1[i] * __expf(ed1[i]);
    s += __shfl_xor(s, 16);
    s += __shfl_xor(s, 32);
    if (q == 0) psm[lo][w] = s;
    __syncthreads();
    if (tid < 16) {
      const f4 pv = *(const f4*)&psm[tid][0];
      logz[b0 + tid] = base + logf(pv[0] + pv[1] + pv[2] + pv[3]);
    }
  }
}

// ---------------------------------------------------------------------------
// Path score, (t,b)-parallel global sum: block = t, lanes = b (coalesced tags/
// mask; em gather stays inside one 256 KB t-slab -> L2/L3 friendly).
// ---------------------------------------------------------------------------
__global__ __launch_bounds__(512) void crf_path_tb(
    const float* __restrict__ em, const int* __restrict__ tags,
    const float* __restrict__ mask, const float* __restrict__ trans,
    float* __restrict__ ws_tb)
{
  const int t = blockIdx.x, b = threadIdx.x;
  const int tg = tags[t * BB + b];
  const float mk = mask[t * BB + b];
  float v = em[((size_t)t * BB + b) * KK + tg] * mk;
  if (t >= 1) {
    const int tgp = tags[(t - 1) * BB + b];
    v += trans[(size_t)tgp * KK + tg] * mk;
  }
  __shared__ float red[8];
#pragma unroll
  for (int off = 32; off; off >>= 1) v += __shfl_xor(v, off);
  if ((b & 63) == 0) red[b >> 6] = v;
  __syncthreads();
  if (b == 0) {
    float s = 0.f;
#pragma unroll
    for (int i = 0; i < 8; ++i) s += red[i];
    ws_tb[t] = s;
  }
}

// per-b boundary terms: start[tag_0] + end[tag_last] (last from mask sum)
__global__ __launch_bounds__(64) void crf_bterm(
    const int* __restrict__ tags, const float* __restrict__ mask,
    const float* __restrict__ start_t, const float* __restrict__ end_t,
    float* __restrict__ ws_bt)
{
  const int b = blockIdx.x, tid = threadIdx.x;
  float ms = 0.f;
  for (int t = tid; t < TT; t += 64) ms += mask[t * BB + b];
#pragma unroll
  for (int off = 32; off; off >>= 1) ms += __shfl_xor(ms, off);
  if (tid == 0) {
    const int last = (int)(ms + 0.5f) - 1;
    ws_bt[b] = start_t[tags[b]] + end_t[tags[(size_t)last * BB + b]];
  }
}

// out = sum_t ws_tb + sum_b (ws_bt - logz)
__global__ __launch_bounds__(1024) void crf_final(
    const float* __restrict__ ws_tb, const float* __restrict__ ws_bt,
    const float* __restrict__ ws_lz, float* __restrict__ out)
{
  const int tid = threadIdx.x;
  float v = ws_tb[tid];
  if (tid < BB) v += ws_bt[tid] - ws_lz[tid];
  __shared__ float red[16];
#pragma unroll
  for (int off = 32; off; off >>= 1) v += __shfl_xor(v, off);
  if ((tid & 63) == 0) red[tid >> 6] = v;
  __syncthreads();
  if (tid == 0) {
    float s = 0.f;
#pragma unroll
    for (int i = 0; i < 16; ++i) s += red[i];
    out[0] = s;
  }
}

extern "C" void kernel_launch(void* const* d_in, const int* in_sizes, int n_in,
                              void* d_out, int out_size, void* d_ws, size_t ws_size,
                              hipStream_t stream) {
  (void)in_sizes; (void)n_in; (void)out_size; (void)ws_size;
  const float* em    = (const float*)d_in[0];
  const int*   tags  = (const int*)  d_in[1];
  const float* mask  = (const float*)d_in[2];
  const float* st    = (const float*)d_in[3];
  const float* trans = (const float*)d_in[4];
  const float* et    = (const float*)d_in[5];
  float* out = (float*)d_out;

  float* ws_tb = (float*)d_ws;   // [1024]
  float* ws_bt = ws_tb + 1024;   // [512]
  float* ws_lz = ws_bt + 512;    // [512]

  crf_path_tb<<<TT, 512, 0, stream>>>(em, tags, mask, trans, ws_tb);
  crf_bterm  <<<BB, 64, 0, stream>>>(tags, mask, st, et, ws_bt);
  crf_forward<<<32, 256, 0, stream>>>(em, mask, st, trans, et, ws_lz);
  crf_final  <<<1, 1024, 0, stream>>>(ws_tb, ws_bt, ws_lz, out);
}